// Round 1
// baseline (194.752 us; speedup 1.0000x reference)
//
#include <hip/hip_runtime.h>

typedef _Float16 f16;
typedef _Float16 f16x4 __attribute__((ext_vector_type(4)));
typedef _Float16 f16x8 __attribute__((ext_vector_type(8)));
typedef float f32x4 __attribute__((ext_vector_type(4)));

#define L2E 1.44269504088896340736f

constexpr int D  = 512;
constexpr int S  = 1024;
constexpr int B  = 4;
constexpr int BS = B * S;   // 4096

// workspace layout (bytes); total ~18.9 MB
constexpr size_t OFF_WT   = 0;                               // 4 * 512*512 f16 (WqT,WkT,WvT,WoT)
constexpr size_t OFF_Q16  = OFF_WT  + 4ull * D * D * 2;
constexpr size_t OFF_K16  = OFF_Q16 + (size_t)BS * D * 2;
constexpr size_t OFF_VT   = OFF_K16 + (size_t)BS * D * 2;    // v, transposed: [b*512+n][S]
constexpr size_t OFF_AT   = OFF_VT  + (size_t)BS * D * 2;    // attention output f16 [BS][D]
constexpr size_t OFF_TAB  = OFF_AT  + (size_t)BS * D * 2;    // float [8][1032]
constexpr size_t OFF_COEF = OFF_TAB + 8ull * 1032 * 4;       // float c[8], d[8]; int flag[8]

// ---------------------------------------------------------------------------
// Kernel 1: weight transpose + f32->f16 convert.  WT[n][k] = (f16)W[k][n]
// ---------------------------------------------------------------------------
__global__ __launch_bounds__(256) void wtrans(const float* __restrict__ Wq, const float* __restrict__ Wk,
                                              const float* __restrict__ Wv, const float* __restrict__ Wo,
                                              f16* __restrict__ WT)
{
    __shared__ float tile[64][65];
    const int z = blockIdx.z;
    const float* __restrict__ W = (z == 0) ? Wq : (z == 1) ? Wk : (z == 2) ? Wv : Wo;
    f16* __restrict__ out = WT + (size_t)z * D * D;
    const int k0 = blockIdx.x * 64, n0 = blockIdx.y * 64;
    for (int i = threadIdx.x; i < 4096; i += 256) {
        int r = i >> 6, c = i & 63;
        tile[r][c] = W[(size_t)(k0 + r) * D + n0 + c];
    }
    __syncthreads();
    for (int i = threadIdx.x; i < 4096; i += 256) {
        int nn = i >> 6, kk = i & 63;
        out[(size_t)(n0 + nn) * D + k0 + kk] = (f16)tile[kk][nn];
    }
}

// ---------------------------------------------------------------------------
// Kernel 2: temporal-bias LUT over td in [0,1], 1025 points, pre-scaled by
// log2(e).  Also detects exact linearity (true when bt1==0, td>=0) and
// emits per-head (c,d) for the 1-fma fast path.
// ---------------------------------------------------------------------------
__global__ __launch_bounds__(256) void build_table(const float* __restrict__ Wt1, const float* __restrict__ bt1,
                                                   const float* __restrict__ Wt2, const float* __restrict__ bt2,
                                                   float* __restrict__ tab, float* __restrict__ coef)
{
    __shared__ int dev[8];
    const int t = threadIdx.x;
    if (t < 8) dev[t] = 0;
    __syncthreads();

    float f0[8], f1[8];
#pragma unroll
    for (int hh = 0; hh < 8; ++hh) { f0[hh] = bt2[hh]; f1[hh] = bt2[hh]; }
    for (int j = 0; j < 32; ++j) {
        float w1 = Wt1[j], b1 = bt1[j];
        float h0 = fmaxf(b1, 0.f);
        float h1 = fmaxf(w1 + b1, 0.f);
#pragma unroll
        for (int hh = 0; hh < 8; ++hh) {
            float w2 = Wt2[j * 8 + hh];
            f0[hh] += h0 * w2;
            f1[hh] += h1 * w2;
        }
    }

    for (int idx = t; idx <= 1024; idx += 256) {
        float tdv = (float)idx * (1.0f / 1024.0f);
        float acc[8];
#pragma unroll
        for (int hh = 0; hh < 8; ++hh) acc[hh] = bt2[hh];
        for (int j = 0; j < 32; ++j) {
            float hv = fmaxf(fmaf(tdv, Wt1[j], bt1[j]), 0.f);
#pragma unroll
            for (int hh = 0; hh < 8; ++hh) acc[hh] += hv * Wt2[j * 8 + hh];
        }
#pragma unroll
        for (int hh = 0; hh < 8; ++hh) {
            float v = acc[hh] * L2E;
            tab[hh * 1032 + idx] = v;
            float linv = (f0[hh] + tdv * (f1[hh] - f0[hh])) * L2E;
            float dvv = fabsf(v - linv);
            atomicMax(&dev[hh], __float_as_int(dvv));
        }
    }
    __syncthreads();
    if (t == 0) {
#pragma unroll
        for (int hh = 0; hh < 8; ++hh) {
            coef[hh]     = (f1[hh] - f0[hh]) * L2E;
            coef[8 + hh] = f0[hh] * L2E;
            ((int*)coef)[16 + hh] = (__int_as_float(dev[hh]) < 1e-4f) ? 1 : 0;
        }
    }
}

// ---------------------------------------------------------------------------
// Kernel 3: fused q/k/v projection GEMM.  C = A(f32) @ W + b  -> f16.
// 128x128 tile, 4 waves (2x2 of 64x64), BK=32, double-buffered LDS.
// z==0: q (scale 0.125*log2e), z==1: k, z==2: v stored transposed vT[b*512+n][j].
// MFMA 16x16x32 f16: A row = lane&15, k = (lane>>4)*8+e ; D col = lane&15,
// row = (lane>>4)*4 + reg   [m89-verified layout].
// ---------------------------------------------------------------------------
__global__ __launch_bounds__(256) void proj_gemm(
    const float* __restrict__ Aq, const float* __restrict__ Ak, const float* __restrict__ Av,
    const f16* __restrict__ WT,
    const float* __restrict__ bq, const float* __restrict__ bk, const float* __restrict__ bv,
    f16* __restrict__ q16, f16* __restrict__ k16, f16* __restrict__ vT, float qscale)
{
    __shared__ f16 As[2][128][40];
    __shared__ f16 Bs[2][128][40];

    const int z = blockIdx.z;
    const float* __restrict__ A    = (z == 0) ? Aq : (z == 1) ? Ak : Av;
    const float* __restrict__ bias = (z == 0) ? bq : (z == 1) ? bk : bv;
    const f16* __restrict__ W      = WT + (size_t)z * D * D;
    const float scale = (z == 0) ? qscale : 1.0f;

    const int t = threadIdx.x;
    const int l = t & 63, w = t >> 6;
    const int i16 = l & 15, g = l >> 4;
    const int wm = w >> 1, wn = w & 1;
    const int m0 = blockIdx.x * 128, n0 = blockIdx.y * 128;

    f32x4 acc[4][4] = {};

    float4 ar[4];
    f16x8  br[2];

    auto load_stage = [&](int kt) {
        const int k0 = kt * 32;
#pragma unroll
        for (int r = 0; r < 4; ++r) {
            int ch = t + 256 * r, row = ch >> 3, c4 = ch & 7;
            ar[r] = *reinterpret_cast<const float4*>(A + (size_t)(m0 + row) * D + k0 + c4 * 4);
        }
#pragma unroll
        for (int r = 0; r < 2; ++r) {
            int ch = t + 256 * r, row = ch >> 2, c8 = ch & 3;
            br[r] = *reinterpret_cast<const f16x8*>(W + (size_t)(n0 + row) * D + k0 + c8 * 8);
        }
    };
    auto write_stage = [&](int buf) {
#pragma unroll
        for (int r = 0; r < 4; ++r) {
            int ch = t + 256 * r, row = ch >> 3, c4 = ch & 7;
            f16x4 hv;
            hv[0] = (f16)ar[r].x; hv[1] = (f16)ar[r].y; hv[2] = (f16)ar[r].z; hv[3] = (f16)ar[r].w;
            *reinterpret_cast<f16x4*>(&As[buf][row][c4 * 4]) = hv;
        }
#pragma unroll
        for (int r = 0; r < 2; ++r) {
            int ch = t + 256 * r, row = ch >> 2, c8 = ch & 3;
            *reinterpret_cast<f16x8*>(&Bs[buf][row][c8 * 8]) = br[r];
        }
    };

    load_stage(0);
    write_stage(0);
    __syncthreads();

    for (int kt = 0; kt < 16; ++kt) {
        const int cur = kt & 1;
        if (kt < 15) load_stage(kt + 1);

        f16x8 af[4], bf[4];
#pragma unroll
        for (int i = 0; i < 4; ++i)
            af[i] = *reinterpret_cast<const f16x8*>(&As[cur][wm * 64 + i * 16 + i16][g * 8]);
#pragma unroll
        for (int j = 0; j < 4; ++j)
            bf[j] = *reinterpret_cast<const f16x8*>(&Bs[cur][wn * 64 + j * 16 + i16][g * 8]);
#pragma unroll
        for (int i = 0; i < 4; ++i)
#pragma unroll
            for (int j = 0; j < 4; ++j)
                acc[i][j] = __builtin_amdgcn_mfma_f32_16x16x32_f16(af[i], bf[j], acc[i][j], 0, 0, 0);

        if (kt < 15) write_stage(cur ^ 1);
        __syncthreads();
    }

    float bvv[4];
#pragma unroll
    for (int j = 0; j < 4; ++j) bvv[j] = bias[n0 + wn * 64 + j * 16 + i16];

    if (z < 2) {
        f16* __restrict__ out = (z == 0) ? q16 : k16;
#pragma unroll
        for (int i = 0; i < 4; ++i) {
#pragma unroll
            for (int j = 0; j < 4; ++j) {
                const int nn = n0 + wn * 64 + j * 16 + i16;
#pragma unroll
                for (int e = 0; e < 4; ++e) {
                    const int mr = m0 + wm * 64 + i * 16 + g * 4 + e;
                    out[(size_t)mr * D + nn] = (f16)((acc[i][j][e] + bvv[j]) * scale);
                }
            }
        }
    } else {
        // transposed store: vT[(b*512 + n)*1024 + j_in_seq]
#pragma unroll
        for (int i = 0; i < 4; ++i) {
            const int mr = m0 + wm * 64 + i * 16 + g * 4;  // 4 consecutive rows via e
            const int bb = mr >> 10, jj = mr & 1023;
#pragma unroll
            for (int j = 0; j < 4; ++j) {
                const int nn = n0 + wn * 64 + j * 16 + i16;
                f16x4 hv;
#pragma unroll
                for (int e = 0; e < 4; ++e) hv[e] = (f16)(acc[i][j][e] + bvv[j]);
                *reinterpret_cast<f16x4*>(vT + ((size_t)(bb * D + nn)) * S + jj) = hv;
            }
        }
    }
}

// ---------------------------------------------------------------------------
// Kernel 4: fused flash attention with temporal bias.
// Block = 128 threads (2 waves), Q-tile 64 rows (32 per wave), KV-tile 32.
// Swapped QK^T: S^T = mfma(K, Q) -> per-lane column i = lane&15 holds a full
// score row slice; softmax stats are lane-local + 2 shfl_xor.
// PV: out^T = mfma(V^T, P^T); V staged from pre-transposed vT with b128s,
// P^T round-trips LDS with packed b64 writes / b128 reads.
// ---------------------------------------------------------------------------
__global__ __launch_bounds__(128, 2) void attn_kernel(
    const f16* __restrict__ q16, const f16* __restrict__ k16, const f16* __restrict__ vT,
    const float* __restrict__ td, const float* __restrict__ tabg, const float* __restrict__ coef,
    f16* __restrict__ out16)
{
    __shared__ f16   Ks[2][32][72];
    __shared__ f16   Vs[2][64][40];
    __shared__ f16   Ps[2][32][40];
    __shared__ float2 Tab[1025];

    // XCD-aware decode: blocks of same b land on same XCD pair (td/K/V L2 reuse)
    const int bid = blockIdx.x;
    const int xs = bid & 7, rest = bid >> 3;
    const int b = xs >> 1;
    const int h = rest & 7;
    const int it = ((rest >> 3) << 1) | (xs & 1);

    const int t = threadIdx.x;
    const int w = t >> 6, l = t & 63;
    const int i16 = l & 15, g = l >> 4;

    const float* __restrict__ th = tabg + h * 1032;
    for (int i = t; i <= 1024; i += 128) {
        float a = th[i];
        float c = th[(i < 1024) ? (i + 1) : 1024];
        Tab[i] = float2{a, c};
    }
    const float cH = coef[h], dH = coef[8 + h];
    const int lin = ((const int*)coef)[16 + h];

    const int ibase = it * 64 + w * 32;

    f16x8 qf[2][2];
#pragma unroll
    for (int fi = 0; fi < 2; ++fi)
#pragma unroll
        for (int kf = 0; kf < 2; ++kf)
            qf[fi][kf] = *reinterpret_cast<const f16x8*>(
                q16 + (size_t)(b * S + ibase + fi * 16 + i16) * D + h * 64 + kf * 32 + g * 8);

    float m2[2] = {-1e30f, -1e30f};
    float ls[2] = {0.f, 0.f};
    f32x4 o[4][2] = {};

    f16x8 sk[2], sv[2];
    int krow[2], kc8[2], vdv[2], vj8[2];
#pragma unroll
    for (int r = 0; r < 2; ++r) {
        int ch = t + 128 * r;
        krow[r] = ch >> 3; kc8[r] = ch & 7;
        vdv[r]  = ch >> 2; vj8[r] = ch & 3;
    }

    auto stage_load = [&](int jt) {
#pragma unroll
        for (int r = 0; r < 2; ++r)
            sk[r] = *reinterpret_cast<const f16x8*>(
                k16 + (size_t)(b * S + jt * 32 + krow[r]) * D + h * 64 + kc8[r] * 8);
#pragma unroll
        for (int r = 0; r < 2; ++r)
            sv[r] = *reinterpret_cast<const f16x8*>(
                vT + (size_t)(b * D + h * 64 + vdv[r]) * S + jt * 32 + vj8[r] * 8);
    };
    auto stage_write = [&](int buf) {
#pragma unroll
        for (int r = 0; r < 2; ++r)
            *reinterpret_cast<f16x8*>(&Ks[buf][krow[r]][kc8[r] * 8]) = sk[r];
#pragma unroll
        for (int r = 0; r < 2; ++r)
            *reinterpret_cast<f16x8*>(&Vs[buf][vdv[r]][vj8[r] * 8]) = sv[r];
    };

    stage_load(0);
    stage_write(0);
    __syncthreads();   // also covers Tab writes

    for (int jt = 0; jt < 32; ++jt) {
        const int cur = jt & 1;
        if (jt < 31) stage_load(jt + 1);

        // ---- S^T = K * Q^T  (D rows = j, cols = i) ----
        f32x4 s[2][2];
#pragma unroll
        for (int fj = 0; fj < 2; ++fj) {
            f16x8 ka0 = *reinterpret_cast<const f16x8*>(&Ks[cur][fj * 16 + i16][g * 8]);
            f16x8 ka1 = *reinterpret_cast<const f16x8*>(&Ks[cur][fj * 16 + i16][32 + g * 8]);
#pragma unroll
            for (int fi = 0; fi < 2; ++fi) {
                f32x4 zz = {0.f, 0.f, 0.f, 0.f};
                zz = __builtin_amdgcn_mfma_f32_16x16x32_f16(ka0, qf[fi][0], zz, 0, 0, 0);
                s[fj][fi] = __builtin_amdgcn_mfma_f32_16x16x32_f16(ka1, qf[fi][1], zz, 0, 0, 0);
            }
        }

        // ---- bias + online softmax (per-lane row i = lane&15) ----
#pragma unroll
        for (int fi = 0; fi < 2; ++fi) {
            const float* __restrict__ tdrow =
                td + (size_t)(b * S + ibase + fi * 16 + i16) * S + jt * 32 + g * 4;
            float pv[2][4];
            float tmax = -1e30f;
#pragma unroll
            for (int fj = 0; fj < 2; ++fj) {
                float4 t4 = *reinterpret_cast<const float4*>(tdrow + fj * 16);
                float tarr[4] = {t4.x, t4.y, t4.z, t4.w};
#pragma unroll
                for (int e = 0; e < 4; ++e) {
                    float u = fminf(fmaxf(tarr[e], 0.f), 1.f);
                    float bias;
                    if (lin) {
                        bias = fmaf(u, cH, dH);
                    } else {
                        float x = u * 1024.f;
                        int ix = (int)x;
                        float fr = x - (float)ix;
                        float2 tv = Tab[ix];
                        bias = fmaf(fr, tv.y - tv.x, tv.x);
                    }
                    float vsc = s[fj][fi][e] + bias;
                    pv[fj][e] = vsc;
                    tmax = fmaxf(tmax, vsc);
                }
            }
            tmax = fmaxf(tmax, __shfl_xor(tmax, 16));
            tmax = fmaxf(tmax, __shfl_xor(tmax, 32));
            float mnew = fmaxf(m2[fi], tmax);
            float alpha = exp2f(m2[fi] - mnew);
            m2[fi] = mnew;

            float rsum = 0.f;
            f16x4 pq[2];
#pragma unroll
            for (int fj = 0; fj < 2; ++fj)
#pragma unroll
                for (int e = 0; e < 4; ++e) {
                    float p = exp2f(pv[fj][e] - mnew);
                    rsum += p;
                    pq[fj][e] = (f16)p;
                }
            rsum += __shfl_xor(rsum, 16);
            rsum += __shfl_xor(rsum, 32);
            ls[fi] = ls[fi] * alpha + rsum;
#pragma unroll
            for (int fv = 0; fv < 4; ++fv) o[fv][fi] *= alpha;

            // store P^T quads: row i, cols j (4 consecutive via reg)
#pragma unroll
            for (int fj = 0; fj < 2; ++fj)
                *reinterpret_cast<f16x4*>(&Ps[w][fi * 16 + i16][fj * 16 + g * 4]) = pq[fj];
        }

        // ---- out^T += V^T * P^T ----
        f16x8 pb[2];
#pragma unroll
        for (int fi = 0; fi < 2; ++fi)
            pb[fi] = *reinterpret_cast<const f16x8*>(&Ps[w][fi * 16 + i16][g * 8]);
#pragma unroll
        for (int fv = 0; fv < 4; ++fv) {
            f16x8 va = *reinterpret_cast<const f16x8*>(&Vs[cur][fv * 16 + i16][g * 8]);
#pragma unroll
            for (int fi = 0; fi < 2; ++fi)
                o[fv][fi] = __builtin_amdgcn_mfma_f32_16x16x32_f16(va, pb[fi], o[fv][fi], 0, 0, 0);
        }

        if (jt < 31) stage_write(cur ^ 1);
        __syncthreads();
    }

    // epilogue: out[i][dv] = o^T / lsum
#pragma unroll
    for (int fi = 0; fi < 2; ++fi) {
        float rl = 1.f / ls[fi];
#pragma unroll
        for (int fv = 0; fv < 4; ++fv) {
            f16x4 hv;
#pragma unroll
            for (int e = 0; e < 4; ++e) hv[e] = (f16)(o[fv][fi][e] * rl);
            *reinterpret_cast<f16x4*>(
                out16 + (size_t)(b * S + ibase + fi * 16 + i16) * D + h * 64 + fv * 16 + g * 4) = hv;
        }
    }
}

// ---------------------------------------------------------------------------
// Kernel 5: output projection.  out(f32) = attn16(f16) @ Wo + bo
// ---------------------------------------------------------------------------
__global__ __launch_bounds__(256) void final_gemm(const f16* __restrict__ A, const f16* __restrict__ WoT,
                                                  const float* __restrict__ bo, float* __restrict__ out)
{
    __shared__ f16 As[2][128][40];
    __shared__ f16 Bs[2][128][40];

    const int t = threadIdx.x;
    const int l = t & 63, w = t >> 6;
    const int i16 = l & 15, g = l >> 4;
    const int wm = w >> 1, wn = w & 1;
    const int m0 = blockIdx.x * 128, n0 = blockIdx.y * 128;

    f32x4 acc[4][4] = {};
    f16x8 ar[2], br[2];

    auto load_stage = [&](int kt) {
        const int k0 = kt * 32;
#pragma unroll
        for (int r = 0; r < 2; ++r) {
            int ch = t + 256 * r, row = ch >> 2, c8 = ch & 3;
            ar[r] = *reinterpret_cast<const f16x8*>(A + (size_t)(m0 + row) * D + k0 + c8 * 8);
            br[r] = *reinterpret_cast<const f16x8*>(WoT + (size_t)(n0 + row) * D + k0 + c8 * 8);
        }
    };
    auto write_stage = [&](int buf) {
#pragma unroll
        for (int r = 0; r < 2; ++r) {
            int ch = t + 256 * r, row = ch >> 2, c8 = ch & 3;
            *reinterpret_cast<f16x8*>(&As[buf][row][c8 * 8]) = ar[r];
            *reinterpret_cast<f16x8*>(&Bs[buf][row][c8 * 8]) = br[r];
        }
    };

    load_stage(0);
    write_stage(0);
    __syncthreads();

    for (int kt = 0; kt < 16; ++kt) {
        const int cur = kt & 1;
        if (kt < 15) load_stage(kt + 1);

        f16x8 af[4], bf[4];
#pragma unroll
        for (int i = 0; i < 4; ++i)
            af[i] = *reinterpret_cast<const f16x8*>(&As[cur][wm * 64 + i * 16 + i16][g * 8]);
#pragma unroll
        for (int j = 0; j < 4; ++j)
            bf[j] = *reinterpret_cast<const f16x8*>(&Bs[cur][wn * 64 + j * 16 + i16][g * 8]);
#pragma unroll
        for (int i = 0; i < 4; ++i)
#pragma unroll
            for (int j = 0; j < 4; ++j)
                acc[i][j] = __builtin_amdgcn_mfma_f32_16x16x32_f16(af[i], bf[j], acc[i][j], 0, 0, 0);

        if (kt < 15) write_stage(cur ^ 1);
        __syncthreads();
    }

    float bvv[4];
#pragma unroll
    for (int j = 0; j < 4; ++j) bvv[j] = bo[n0 + wn * 64 + j * 16 + i16];

#pragma unroll
    for (int i = 0; i < 4; ++i) {
#pragma unroll
        for (int j = 0; j < 4; ++j) {
            const int nn = n0 + wn * 64 + j * 16 + i16;
#pragma unroll
            for (int e = 0; e < 4; ++e) {
                const int mr = m0 + wm * 64 + i * 16 + g * 4 + e;
                out[(size_t)mr * D + nn] = acc[i][j][e] + bvv[j];
            }
        }
    }
}

// ---------------------------------------------------------------------------
extern "C" void kernel_launch(void* const* d_in, const int* in_sizes, int n_in,
                              void* d_out, int out_size, void* d_ws, size_t ws_size,
                              hipStream_t stream)
{
    (void)in_sizes; (void)n_in; (void)out_size; (void)ws_size; // needs ~19 MB of ws

    const float* query = (const float*)d_in[0];
    const float* key_  = (const float*)d_in[1];
    const float* value = (const float*)d_in[2];
    const float* td    = (const float*)d_in[3];
    const float* Wq  = (const float*)d_in[4];  const float* bq  = (const float*)d_in[5];
    const float* Wk  = (const float*)d_in[6];  const float* bk  = (const float*)d_in[7];
    const float* Wv  = (const float*)d_in[8];  const float* bv  = (const float*)d_in[9];
    const float* Wo  = (const float*)d_in[10]; const float* bo  = (const float*)d_in[11];
    const float* Wt1 = (const float*)d_in[12]; const float* bt1 = (const float*)d_in[13];
    const float* Wt2 = (const float*)d_in[14]; const float* bt2 = (const float*)d_in[15];
    float* out = (float*)d_out;

    char* ws = (char*)d_ws;
    f16*   WT   = (f16*)(ws + OFF_WT);
    f16*   q16  = (f16*)(ws + OFF_Q16);
    f16*   k16  = (f16*)(ws + OFF_K16);
    f16*   vT   = (f16*)(ws + OFF_VT);
    f16*   at16 = (f16*)(ws + OFF_AT);
    float* tab  = (float*)(ws + OFF_TAB);
    float* coef = (float*)(ws + OFF_COEF);

    wtrans<<<dim3(8, 8, 4), 256, 0, stream>>>(Wq, Wk, Wv, Wo, WT);
    build_table<<<1, 256, 0, stream>>>(Wt1, bt1, Wt2, bt2, tab, coef);
    proj_gemm<<<dim3(32, 4, 3), 256, 0, stream>>>(query, key_, value, WT, bq, bk, bv,
                                                  q16, k16, vT, 0.125f * L2E);
    attn_kernel<<<512, 128, 0, stream>>>(q16, k16, vT, td, tab, coef, at16);
    final_gemm<<<dim3(32, 4), 256, 0, stream>>>(at16, WT + 3ull * (size_t)D * D, bo, out);
}

// Round 2
// 140.859 us; speedup vs baseline: 1.3826x; 1.3826x over previous
//
#include <hip/hip_runtime.h>

typedef _Float16 f16;
typedef _Float16 f16x4 __attribute__((ext_vector_type(4)));
typedef _Float16 f16x8 __attribute__((ext_vector_type(8)));
typedef float f32x4 __attribute__((ext_vector_type(4)));

#define L2E 1.44269504088896340736f

constexpr int D  = 512;
constexpr int S  = 1024;
constexpr int B  = 4;
constexpr int BS = B * S;   // 4096

// workspace layout (bytes); total ~18.9 MB
constexpr size_t OFF_WT   = 0;                               // 4 * 512*512 f16 (WqT,WkT,WvT,WoT)
constexpr size_t OFF_Q16  = OFF_WT  + 4ull * D * D * 2;
constexpr size_t OFF_K16  = OFF_Q16 + (size_t)BS * D * 2;
constexpr size_t OFF_VT   = OFF_K16 + (size_t)BS * D * 2;    // v, transposed: [b*512+n][S]
constexpr size_t OFF_AT   = OFF_VT  + (size_t)BS * D * 2;    // attention output f16 [BS][D]
constexpr size_t OFF_TAB  = OFF_AT  + (size_t)BS * D * 2;    // float [8][1032]
constexpr size_t OFF_COEF = OFF_TAB + 8ull * 1032 * 4;       // float c[8], d[8]; int flag[8]

// ---------------------------------------------------------------------------
// Kernel 1: weight transpose + f32->f16 convert.  WT[n][k] = (f16)W[k][n]
// ---------------------------------------------------------------------------
__global__ __launch_bounds__(256) void wtrans(const float* __restrict__ Wq, const float* __restrict__ Wk,
                                              const float* __restrict__ Wv, const float* __restrict__ Wo,
                                              f16* __restrict__ WT)
{
    __shared__ float tile[64][65];
    const int z = blockIdx.z;
    const float* __restrict__ W = (z == 0) ? Wq : (z == 1) ? Wk : (z == 2) ? Wv : Wo;
    f16* __restrict__ out = WT + (size_t)z * D * D;
    const int k0 = blockIdx.x * 64, n0 = blockIdx.y * 64;
    for (int i = threadIdx.x; i < 4096; i += 256) {
        int r = i >> 6, c = i & 63;
        tile[r][c] = W[(size_t)(k0 + r) * D + n0 + c];
    }
    __syncthreads();
    for (int i = threadIdx.x; i < 4096; i += 256) {
        int nn = i >> 6, kk = i & 63;
        out[(size_t)(n0 + nn) * D + k0 + kk] = (f16)tile[kk][nn];
    }
}

// ---------------------------------------------------------------------------
// Kernel 2: temporal-bias LUT over td in [0,1], 1025 points, pre-scaled by
// log2(e).  Weights staged in LDS (the previous version re-read them from
// global in the inner loop -> 90us latency-bound; this is ~3us).
// Also detects exact linearity (true when bt1==0, td>=0) and emits per-head
// (c,d) for the 1-fma fast path.
// ---------------------------------------------------------------------------
__global__ __launch_bounds__(1024) void build_table(const float* __restrict__ Wt1, const float* __restrict__ bt1,
                                                    const float* __restrict__ Wt2, const float* __restrict__ bt2,
                                                    float* __restrict__ tab, float* __restrict__ coef)
{
    __shared__ float w1s[32], b1s[32], w2s[256], b2s[8];
    __shared__ int dev[8];
    const int t = threadIdx.x;
    if (t < 32)               { w1s[t] = Wt1[t]; b1s[t] = bt1[t]; }
    if (t >= 64 && t < 320)   w2s[t - 64] = Wt2[t - 64];
    if (t >= 320 && t < 328)  b2s[t - 320] = bt2[t - 320];
    if (t < 8) dev[t] = 0;
    __syncthreads();

    // endpoint values for the linear model (computed per-thread from LDS; cheap)
    float f0[8], f1[8];
#pragma unroll
    for (int hh = 0; hh < 8; ++hh) { f0[hh] = b2s[hh]; f1[hh] = b2s[hh]; }
#pragma unroll 4
    for (int j = 0; j < 32; ++j) {
        float w1 = w1s[j], b1 = b1s[j];
        float h0 = fmaxf(b1, 0.f);
        float h1 = fmaxf(w1 + b1, 0.f);
#pragma unroll
        for (int hh = 0; hh < 8; ++hh) {
            float w2 = w2s[j * 8 + hh];
            f0[hh] += h0 * w2;
            f1[hh] += h1 * w2;
        }
    }

    for (int idx = t; idx <= 1024; idx += 1024) {
        float tdv = (float)idx * (1.0f / 1024.0f);
        float acc[8];
#pragma unroll
        for (int hh = 0; hh < 8; ++hh) acc[hh] = b2s[hh];
#pragma unroll 4
        for (int j = 0; j < 32; ++j) {
            float hv = fmaxf(fmaf(tdv, w1s[j], b1s[j]), 0.f);
#pragma unroll
            for (int hh = 0; hh < 8; ++hh) acc[hh] += hv * w2s[j * 8 + hh];
        }
#pragma unroll
        for (int hh = 0; hh < 8; ++hh) {
            float v = acc[hh] * L2E;
            tab[hh * 1032 + idx] = v;
            float linv = (f0[hh] + tdv * (f1[hh] - f0[hh])) * L2E;
            float dvv = fabsf(v - linv);
            atomicMax(&dev[hh], __float_as_int(dvv));
        }
    }
    __syncthreads();
    if (t == 0) {
#pragma unroll
        for (int hh = 0; hh < 8; ++hh) {
            coef[hh]     = (f1[hh] - f0[hh]) * L2E;
            coef[8 + hh] = f0[hh] * L2E;
            ((int*)coef)[16 + hh] = (__int_as_float(dev[hh]) < 1e-4f) ? 1 : 0;
        }
    }
}

// ---------------------------------------------------------------------------
// Kernel 3: fused q/k/v projection GEMM.  C = A(f32) @ W + b  -> f16.
// 128x128 tile, 4 waves (2x2 of 64x64), BK=32, double-buffered LDS.
// z==0: q (scale 0.125*log2e), z==1: k, z==2: v stored transposed vT[b*512+n][j].
// MFMA 16x16x32 f16: A row = lane&15, k = (lane>>4)*8+e ; D col = lane&15,
// row = (lane>>4)*4 + reg   [m89-verified layout].
// ---------------------------------------------------------------------------
__global__ __launch_bounds__(256) void proj_gemm(
    const float* __restrict__ Aq, const float* __restrict__ Ak, const float* __restrict__ Av,
    const f16* __restrict__ WT,
    const float* __restrict__ bq, const float* __restrict__ bk, const float* __restrict__ bv,
    f16* __restrict__ q16, f16* __restrict__ k16, f16* __restrict__ vT, float qscale)
{
    __shared__ f16 As[2][128][40];
    __shared__ f16 Bs[2][128][40];

    const int z = blockIdx.z;
    const float* __restrict__ A    = (z == 0) ? Aq : (z == 1) ? Ak : Av;
    const float* __restrict__ bias = (z == 0) ? bq : (z == 1) ? bk : bv;
    const f16* __restrict__ W      = WT + (size_t)z * D * D;
    const float scale = (z == 0) ? qscale : 1.0f;

    const int t = threadIdx.x;
    const int l = t & 63, w = t >> 6;
    const int i16 = l & 15, g = l >> 4;
    const int wm = w >> 1, wn = w & 1;
    const int m0 = blockIdx.x * 128, n0 = blockIdx.y * 128;

    f32x4 acc[4][4] = {};

    float4 ar[4];
    f16x8  br[2];

    auto load_stage = [&](int kt) {
        const int k0 = kt * 32;
#pragma unroll
        for (int r = 0; r < 4; ++r) {
            int ch = t + 256 * r, row = ch >> 3, c4 = ch & 7;
            ar[r] = *reinterpret_cast<const float4*>(A + (size_t)(m0 + row) * D + k0 + c4 * 4);
        }
#pragma unroll
        for (int r = 0; r < 2; ++r) {
            int ch = t + 256 * r, row = ch >> 2, c8 = ch & 3;
            br[r] = *reinterpret_cast<const f16x8*>(W + (size_t)(n0 + row) * D + k0 + c8 * 8);
        }
    };
    auto write_stage = [&](int buf) {
#pragma unroll
        for (int r = 0; r < 4; ++r) {
            int ch = t + 256 * r, row = ch >> 3, c4 = ch & 7;
            f16x4 hv;
            hv[0] = (f16)ar[r].x; hv[1] = (f16)ar[r].y; hv[2] = (f16)ar[r].z; hv[3] = (f16)ar[r].w;
            *reinterpret_cast<f16x4*>(&As[buf][row][c4 * 4]) = hv;
        }
#pragma unroll
        for (int r = 0; r < 2; ++r) {
            int ch = t + 256 * r, row = ch >> 2, c8 = ch & 3;
            *reinterpret_cast<f16x8*>(&Bs[buf][row][c8 * 8]) = br[r];
        }
    };

    load_stage(0);
    write_stage(0);
    __syncthreads();

    for (int kt = 0; kt < 16; ++kt) {
        const int cur = kt & 1;
        if (kt < 15) load_stage(kt + 1);

        f16x8 af[4], bf[4];
#pragma unroll
        for (int i = 0; i < 4; ++i)
            af[i] = *reinterpret_cast<const f16x8*>(&As[cur][wm * 64 + i * 16 + i16][g * 8]);
#pragma unroll
        for (int j = 0; j < 4; ++j)
            bf[j] = *reinterpret_cast<const f16x8*>(&Bs[cur][wn * 64 + j * 16 + i16][g * 8]);
#pragma unroll
        for (int i = 0; i < 4; ++i)
#pragma unroll
            for (int j = 0; j < 4; ++j)
                acc[i][j] = __builtin_amdgcn_mfma_f32_16x16x32_f16(af[i], bf[j], acc[i][j], 0, 0, 0);

        if (kt < 15) write_stage(cur ^ 1);
        __syncthreads();
    }

    float bvv[4];
#pragma unroll
    for (int j = 0; j < 4; ++j) bvv[j] = bias[n0 + wn * 64 + j * 16 + i16];

    if (z < 2) {
        f16* __restrict__ out = (z == 0) ? q16 : k16;
#pragma unroll
        for (int i = 0; i < 4; ++i) {
#pragma unroll
            for (int j = 0; j < 4; ++j) {
                const int nn = n0 + wn * 64 + j * 16 + i16;
#pragma unroll
                for (int e = 0; e < 4; ++e) {
                    const int mr = m0 + wm * 64 + i * 16 + g * 4 + e;
                    out[(size_t)mr * D + nn] = (f16)((acc[i][j][e] + bvv[j]) * scale);
                }
            }
        }
    } else {
        // transposed store: vT[(b*512 + n)*1024 + j_in_seq]
#pragma unroll
        for (int i = 0; i < 4; ++i) {
            const int mr = m0 + wm * 64 + i * 16 + g * 4;  // 4 consecutive rows via e
            const int bb = mr >> 10, jj = mr & 1023;
#pragma unroll
            for (int j = 0; j < 4; ++j) {
                const int nn = n0 + wn * 64 + j * 16 + i16;
                f16x4 hv;
#pragma unroll
                for (int e = 0; e < 4; ++e) hv[e] = (f16)(acc[i][j][e] + bvv[j]);
                *reinterpret_cast<f16x4*>(vT + ((size_t)(bb * D + nn)) * S + jj) = hv;
            }
        }
    }
}

// ---------------------------------------------------------------------------
// Kernel 4: fused flash attention with temporal bias.
// Block = 128 threads (2 waves), Q-tile 64 rows (32 per wave), KV-tile 32.
// Swapped QK^T: S^T = mfma(K, Q) -> per-lane column i = lane&15 holds a full
// score row slice; softmax stats are lane-local + 2 shfl_xor.
// PV: out^T = mfma(V^T, P^T); V staged from pre-transposed vT with b128s,
// P^T round-trips LDS with packed b64 writes / b128 reads.
// ---------------------------------------------------------------------------
__global__ __launch_bounds__(128, 2) void attn_kernel(
    const f16* __restrict__ q16, const f16* __restrict__ k16, const f16* __restrict__ vT,
    const float* __restrict__ td, const float* __restrict__ tabg, const float* __restrict__ coef,
    f16* __restrict__ out16)
{
    __shared__ f16   Ks[2][32][72];
    __shared__ f16   Vs[2][64][40];
    __shared__ f16   Ps[2][32][40];
    __shared__ float2 Tab[1025];

    // XCD-aware decode: blocks of same b land on same XCD pair (td/K/V L2 reuse)
    const int bid = blockIdx.x;
    const int xs = bid & 7, rest = bid >> 3;
    const int b = xs >> 1;
    const int h = rest & 7;
    const int it = ((rest >> 3) << 1) | (xs & 1);

    const int t = threadIdx.x;
    const int w = t >> 6, l = t & 63;
    const int i16 = l & 15, g = l >> 4;

    const float* __restrict__ th = tabg + h * 1032;
    for (int i = t; i <= 1024; i += 128) {
        float a = th[i];
        float c = th[(i < 1024) ? (i + 1) : 1024];
        Tab[i] = float2{a, c};
    }
    const float cH = coef[h], dH = coef[8 + h];
    const int lin = ((const int*)coef)[16 + h];

    const int ibase = it * 64 + w * 32;

    f16x8 qf[2][2];
#pragma unroll
    for (int fi = 0; fi < 2; ++fi)
#pragma unroll
        for (int kf = 0; kf < 2; ++kf)
            qf[fi][kf] = *reinterpret_cast<const f16x8*>(
                q16 + (size_t)(b * S + ibase + fi * 16 + i16) * D + h * 64 + kf * 32 + g * 8);

    float m2[2] = {-1e30f, -1e30f};
    float ls[2] = {0.f, 0.f};
    f32x4 o[4][2] = {};

    f16x8 sk[2], sv[2];
    int krow[2], kc8[2], vdv[2], vj8[2];
#pragma unroll
    for (int r = 0; r < 2; ++r) {
        int ch = t + 128 * r;
        krow[r] = ch >> 3; kc8[r] = ch & 7;
        vdv[r]  = ch >> 2; vj8[r] = ch & 3;
    }

    auto stage_load = [&](int jt) {
#pragma unroll
        for (int r = 0; r < 2; ++r)
            sk[r] = *reinterpret_cast<const f16x8*>(
                k16 + (size_t)(b * S + jt * 32 + krow[r]) * D + h * 64 + kc8[r] * 8);
#pragma unroll
        for (int r = 0; r < 2; ++r)
            sv[r] = *reinterpret_cast<const f16x8*>(
                vT + (size_t)(b * D + h * 64 + vdv[r]) * S + jt * 32 + vj8[r] * 8);
    };
    auto stage_write = [&](int buf) {
#pragma unroll
        for (int r = 0; r < 2; ++r)
            *reinterpret_cast<f16x8*>(&Ks[buf][krow[r]][kc8[r] * 8]) = sk[r];
#pragma unroll
        for (int r = 0; r < 2; ++r)
            *reinterpret_cast<f16x8*>(&Vs[buf][vdv[r]][vj8[r] * 8]) = sv[r];
    };

    stage_load(0);
    stage_write(0);
    __syncthreads();   // also covers Tab writes

    for (int jt = 0; jt < 32; ++jt) {
        const int cur = jt & 1;
        if (jt < 31) stage_load(jt + 1);

        // ---- S^T = K * Q^T  (D rows = j, cols = i) ----
        f32x4 s[2][2];
#pragma unroll
        for (int fj = 0; fj < 2; ++fj) {
            f16x8 ka0 = *reinterpret_cast<const f16x8*>(&Ks[cur][fj * 16 + i16][g * 8]);
            f16x8 ka1 = *reinterpret_cast<const f16x8*>(&Ks[cur][fj * 16 + i16][32 + g * 8]);
#pragma unroll
            for (int fi = 0; fi < 2; ++fi) {
                f32x4 zz = {0.f, 0.f, 0.f, 0.f};
                zz = __builtin_amdgcn_mfma_f32_16x16x32_f16(ka0, qf[fi][0], zz, 0, 0, 0);
                s[fj][fi] = __builtin_amdgcn_mfma_f32_16x16x32_f16(ka1, qf[fi][1], zz, 0, 0, 0);
            }
        }

        // ---- bias + online softmax (per-lane row i = lane&15) ----
#pragma unroll
        for (int fi = 0; fi < 2; ++fi) {
            const float* __restrict__ tdrow =
                td + (size_t)(b * S + ibase + fi * 16 + i16) * S + jt * 32 + g * 4;
            float pv[2][4];
            float tmax = -1e30f;
#pragma unroll
            for (int fj = 0; fj < 2; ++fj) {
                float4 t4 = *reinterpret_cast<const float4*>(tdrow + fj * 16);
                float tarr[4] = {t4.x, t4.y, t4.z, t4.w};
#pragma unroll
                for (int e = 0; e < 4; ++e) {
                    float u = fminf(fmaxf(tarr[e], 0.f), 1.f);
                    float bias;
                    if (lin) {
                        bias = fmaf(u, cH, dH);
                    } else {
                        float x = u * 1024.f;
                        int ix = (int)x;
                        float fr = x - (float)ix;
                        float2 tv = Tab[ix];
                        bias = fmaf(fr, tv.y - tv.x, tv.x);
                    }
                    float vsc = s[fj][fi][e] + bias;
                    pv[fj][e] = vsc;
                    tmax = fmaxf(tmax, vsc);
                }
            }
            tmax = fmaxf(tmax, __shfl_xor(tmax, 16));
            tmax = fmaxf(tmax, __shfl_xor(tmax, 32));
            float mnew = fmaxf(m2[fi], tmax);
            float alpha = exp2f(m2[fi] - mnew);
            m2[fi] = mnew;

            float rsum = 0.f;
            f16x4 pq[2];
#pragma unroll
            for (int fj = 0; fj < 2; ++fj)
#pragma unroll
                for (int e = 0; e < 4; ++e) {
                    float p = exp2f(pv[fj][e] - mnew);
                    rsum += p;
                    pq[fj][e] = (f16)p;
                }
            rsum += __shfl_xor(rsum, 16);
            rsum += __shfl_xor(rsum, 32);
            ls[fi] = ls[fi] * alpha + rsum;
#pragma unroll
            for (int fv = 0; fv < 4; ++fv) o[fv][fi] *= alpha;

            // store P^T quads: row i, cols j (4 consecutive via reg)
#pragma unroll
            for (int fj = 0; fj < 2; ++fj)
                *reinterpret_cast<f16x4*>(&Ps[w][fi * 16 + i16][fj * 16 + g * 4]) = pq[fj];
        }

        // ---- out^T += V^T * P^T ----
        f16x8 pb[2];
#pragma unroll
        for (int fi = 0; fi < 2; ++fi)
            pb[fi] = *reinterpret_cast<const f16x8*>(&Ps[w][fi * 16 + i16][g * 8]);
#pragma unroll
        for (int fv = 0; fv < 4; ++fv) {
            f16x8 va = *reinterpret_cast<const f16x8*>(&Vs[cur][fv * 16 + i16][g * 8]);
#pragma unroll
            for (int fi = 0; fi < 2; ++fi)
                o[fv][fi] = __builtin_amdgcn_mfma_f32_16x16x32_f16(va, pb[fi], o[fv][fi], 0, 0, 0);
        }

        if (jt < 31) stage_write(cur ^ 1);
        __syncthreads();
    }

    // epilogue: out[i][dv] = o^T / lsum
#pragma unroll
    for (int fi = 0; fi < 2; ++fi) {
        float rl = 1.f / ls[fi];
#pragma unroll
        for (int fv = 0; fv < 4; ++fv) {
            f16x4 hv;
#pragma unroll
            for (int e = 0; e < 4; ++e) hv[e] = (f16)(o[fv][fi][e] * rl);
            *reinterpret_cast<f16x4*>(
                out16 + (size_t)(b * S + ibase + fi * 16 + i16) * D + h * 64 + fv * 16 + g * 4) = hv;
        }
    }
}

// ---------------------------------------------------------------------------
// Kernel 5: output projection.  out(f32) = attn16(f16) @ Wo + bo
// ---------------------------------------------------------------------------
__global__ __launch_bounds__(256) void final_gemm(const f16* __restrict__ A, const f16* __restrict__ WoT,
                                                  const float* __restrict__ bo, float* __restrict__ out)
{
    __shared__ f16 As[2][128][40];
    __shared__ f16 Bs[2][128][40];

    const int t = threadIdx.x;
    const int l = t & 63, w = t >> 6;
    const int i16 = l & 15, g = l >> 4;
    const int wm = w >> 1, wn = w & 1;
    const int m0 = blockIdx.x * 128, n0 = blockIdx.y * 128;

    f32x4 acc[4][4] = {};
    f16x8 ar[2], br[2];

    auto load_stage = [&](int kt) {
        const int k0 = kt * 32;
#pragma unroll
        for (int r = 0; r < 2; ++r) {
            int ch = t + 256 * r, row = ch >> 2, c8 = ch & 3;
            ar[r] = *reinterpret_cast<const f16x8*>(A + (size_t)(m0 + row) * D + k0 + c8 * 8);
            br[r] = *reinterpret_cast<const f16x8*>(WoT + (size_t)(n0 + row) * D + k0 + c8 * 8);
        }
    };
    auto write_stage = [&](int buf) {
#pragma unroll
        for (int r = 0; r < 2; ++r) {
            int ch = t + 256 * r, row = ch >> 2, c8 = ch & 3;
            *reinterpret_cast<f16x8*>(&As[buf][row][c8 * 8]) = ar[r];
            *reinterpret_cast<f16x8*>(&Bs[buf][row][c8 * 8]) = br[r];
        }
    };

    load_stage(0);
    write_stage(0);
    __syncthreads();

    for (int kt = 0; kt < 16; ++kt) {
        const int cur = kt & 1;
        if (kt < 15) load_stage(kt + 1);

        f16x8 af[4], bf[4];
#pragma unroll
        for (int i = 0; i < 4; ++i)
            af[i] = *reinterpret_cast<const f16x8*>(&As[cur][wm * 64 + i * 16 + i16][g * 8]);
#pragma unroll
        for (int j = 0; j < 4; ++j)
            bf[j] = *reinterpret_cast<const f16x8*>(&Bs[cur][wn * 64 + j * 16 + i16][g * 8]);
#pragma unroll
        for (int i = 0; i < 4; ++i)
#pragma unroll
            for (int j = 0; j < 4; ++j)
                acc[i][j] = __builtin_amdgcn_mfma_f32_16x16x32_f16(af[i], bf[j], acc[i][j], 0, 0, 0);

        if (kt < 15) write_stage(cur ^ 1);
        __syncthreads();
    }

    float bvv[4];
#pragma unroll
    for (int j = 0; j < 4; ++j) bvv[j] = bo[n0 + wn * 64 + j * 16 + i16];

#pragma unroll
    for (int i = 0; i < 4; ++i) {
#pragma unroll
        for (int j = 0; j < 4; ++j) {
            const int nn = n0 + wn * 64 + j * 16 + i16;
#pragma unroll
            for (int e = 0; e < 4; ++e) {
                const int mr = m0 + wm * 64 + i * 16 + g * 4 + e;
                out[(size_t)mr * D + nn] = acc[i][j][e] + bvv[j];
            }
        }
    }
}

// ---------------------------------------------------------------------------
extern "C" void kernel_launch(void* const* d_in, const int* in_sizes, int n_in,
                              void* d_out, int out_size, void* d_ws, size_t ws_size,
                              hipStream_t stream)
{
    (void)in_sizes; (void)n_in; (void)out_size; (void)ws_size; // needs ~19 MB of ws

    const float* query = (const float*)d_in[0];
    const float* key_  = (const float*)d_in[1];
    const float* value = (const float*)d_in[2];
    const float* td    = (const float*)d_in[3];
    const float* Wq  = (const float*)d_in[4];  const float* bq  = (const float*)d_in[5];
    const float* Wk  = (const float*)d_in[6];  const float* bk  = (const float*)d_in[7];
    const float* Wv  = (const float*)d_in[8];  const float* bv  = (const float*)d_in[9];
    const float* Wo  = (const float*)d_in[10]; const float* bo  = (const float*)d_in[11];
    const float* Wt1 = (const float*)d_in[12]; const float* bt1 = (const float*)d_in[13];
    const float* Wt2 = (const float*)d_in[14]; const float* bt2 = (const float*)d_in[15];
    float* out = (float*)d_out;

    char* ws = (char*)d_ws;
    f16*   WT   = (f16*)(ws + OFF_WT);
    f16*   q16  = (f16*)(ws + OFF_Q16);
    f16*   k16  = (f16*)(ws + OFF_K16);
    f16*   vT   = (f16*)(ws + OFF_VT);
    f16*   at16 = (f16*)(ws + OFF_AT);
    float* tab  = (float*)(ws + OFF_TAB);
    float* coef = (float*)(ws + OFF_COEF);

    wtrans<<<dim3(8, 8, 4), 256, 0, stream>>>(Wq, Wk, Wv, Wo, WT);
    build_table<<<1, 1024, 0, stream>>>(Wt1, bt1, Wt2, bt2, tab, coef);
    proj_gemm<<<dim3(32, 4, 3), 256, 0, stream>>>(query, key_, value, WT, bq, bk, bv,
                                                  q16, k16, vT, 0.125f * L2E);
    attn_kernel<<<512, 128, 0, stream>>>(q16, k16, vT, td, tab, coef, at16);
    final_gemm<<<dim3(32, 4), 256, 0, stream>>>(at16, WT + 3ull * (size_t)D * D, bo, out);
}

// Round 3
// 104.815 us; speedup vs baseline: 1.8581x; 1.3439x over previous
//
#include <hip/hip_runtime.h>

typedef _Float16 f16;
typedef _Float16 f16x4 __attribute__((ext_vector_type(4)));
typedef _Float16 f16x8 __attribute__((ext_vector_type(8)));
typedef float f32x4 __attribute__((ext_vector_type(4)));

#define L2E 1.44269504088896340736f

constexpr int D  = 512;
constexpr int S  = 1024;
constexpr int B  = 4;
constexpr int BS = B * S;   // 4096

// workspace layout (bytes); total ~18.9 MB
constexpr size_t OFF_WT   = 0;                               // 4 * 512*512 f16 (WqT,WkT,WvT,WoT)
constexpr size_t OFF_Q16  = OFF_WT  + 4ull * D * D * 2;
constexpr size_t OFF_K16  = OFF_Q16 + (size_t)BS * D * 2;
constexpr size_t OFF_VT   = OFF_K16 + (size_t)BS * D * 2;    // v, transposed: [b*512+n][S]
constexpr size_t OFF_AT   = OFF_VT  + (size_t)BS * D * 2;    // attention output f16 [BS][D]
constexpr size_t OFF_TAB  = OFF_AT  + (size_t)BS * D * 2;    // float [8][1032]
constexpr size_t OFF_COEF = OFF_TAB + 8ull * 1032 * 4;       // float c[8], d[8]; int flag[8]

// ---------------------------------------------------------------------------
// Kernel 1: weight transpose + f32->f16 convert.  WT[n][k] = (f16)W[k][n]
// ---------------------------------------------------------------------------
__global__ __launch_bounds__(256) void wtrans(const float* __restrict__ Wq, const float* __restrict__ Wk,
                                              const float* __restrict__ Wv, const float* __restrict__ Wo,
                                              f16* __restrict__ WT)
{
    __shared__ float tile[64][65];
    const int z = blockIdx.z;
    const float* __restrict__ W = (z == 0) ? Wq : (z == 1) ? Wk : (z == 2) ? Wv : Wo;
    f16* __restrict__ out = WT + (size_t)z * D * D;
    const int k0 = blockIdx.x * 64, n0 = blockIdx.y * 64;
    for (int i = threadIdx.x; i < 4096; i += 256) {
        int r = i >> 6, c = i & 63;
        tile[r][c] = W[(size_t)(k0 + r) * D + n0 + c];
    }
    __syncthreads();
    for (int i = threadIdx.x; i < 4096; i += 256) {
        int nn = i >> 6, kk = i & 63;
        out[(size_t)(n0 + nn) * D + k0 + kk] = (f16)tile[kk][nn];
    }
}

// ---------------------------------------------------------------------------
// Kernel 2: temporal-bias LUT over td in [0,1], 1025 points, pre-scaled by
// log2(e).  Weights staged in LDS.  Also detects exact linearity (true when
// bt1==0, td>=0) and emits per-head (c,d) for the 1-fma fast path.
// ---------------------------------------------------------------------------
__global__ __launch_bounds__(1024) void build_table(const float* __restrict__ Wt1, const float* __restrict__ bt1,
                                                    const float* __restrict__ Wt2, const float* __restrict__ bt2,
                                                    float* __restrict__ tab, float* __restrict__ coef)
{
    __shared__ float w1s[32], b1s[32], w2s[256], b2s[8];
    __shared__ int dev[8];
    const int t = threadIdx.x;
    if (t < 32)               { w1s[t] = Wt1[t]; b1s[t] = bt1[t]; }
    if (t >= 64 && t < 320)   w2s[t - 64] = Wt2[t - 64];
    if (t >= 320 && t < 328)  b2s[t - 320] = bt2[t - 320];
    if (t < 8) dev[t] = 0;
    __syncthreads();

    // endpoint values for the linear model (computed per-thread from LDS; cheap)
    float f0[8], f1[8];
#pragma unroll
    for (int hh = 0; hh < 8; ++hh) { f0[hh] = b2s[hh]; f1[hh] = b2s[hh]; }
#pragma unroll 4
    for (int j = 0; j < 32; ++j) {
        float w1 = w1s[j], b1 = b1s[j];
        float h0 = fmaxf(b1, 0.f);
        float h1 = fmaxf(w1 + b1, 0.f);
#pragma unroll
        for (int hh = 0; hh < 8; ++hh) {
            float w2 = w2s[j * 8 + hh];
            f0[hh] += h0 * w2;
            f1[hh] += h1 * w2;
        }
    }

    for (int idx = t; idx <= 1024; idx += 1024) {
        float tdv = (float)idx * (1.0f / 1024.0f);
        float acc[8];
#pragma unroll
        for (int hh = 0; hh < 8; ++hh) acc[hh] = b2s[hh];
#pragma unroll 4
        for (int j = 0; j < 32; ++j) {
            float hv = fmaxf(fmaf(tdv, w1s[j], b1s[j]), 0.f);
#pragma unroll
            for (int hh = 0; hh < 8; ++hh) acc[hh] += hv * w2s[j * 8 + hh];
        }
#pragma unroll
        for (int hh = 0; hh < 8; ++hh) {
            float v = acc[hh] * L2E;
            tab[hh * 1032 + idx] = v;
            float linv = (f0[hh] + tdv * (f1[hh] - f0[hh])) * L2E;
            float dvv = fabsf(v - linv);
            atomicMax(&dev[hh], __float_as_int(dvv));
        }
    }
    __syncthreads();
    if (t == 0) {
#pragma unroll
        for (int hh = 0; hh < 8; ++hh) {
            coef[hh]     = (f1[hh] - f0[hh]) * L2E;
            coef[8 + hh] = f0[hh] * L2E;
            ((int*)coef)[16 + hh] = (__int_as_float(dev[hh]) < 1e-4f) ? 1 : 0;
        }
    }
}

// ---------------------------------------------------------------------------
// Kernel 3: fused q/k/v projection GEMM.  C = A(f32) @ W + b  -> f16.
// 128x128 tile, 4 waves (2x2 of 64x64), BK=32, double-buffered LDS.
// z==0: q (scale 0.125*log2e), z==1: k, z==2: v stored transposed vT[b*512+n][j].
// ---------------------------------------------------------------------------
__global__ __launch_bounds__(256) void proj_gemm(
    const float* __restrict__ Aq, const float* __restrict__ Ak, const float* __restrict__ Av,
    const f16* __restrict__ WT,
    const float* __restrict__ bq, const float* __restrict__ bk, const float* __restrict__ bv,
    f16* __restrict__ q16, f16* __restrict__ k16, f16* __restrict__ vT, float qscale)
{
    __shared__ f16 As[2][128][40];
    __shared__ f16 Bs[2][128][40];

    const int z = blockIdx.z;
    const float* __restrict__ A    = (z == 0) ? Aq : (z == 1) ? Ak : Av;
    const float* __restrict__ bias = (z == 0) ? bq : (z == 1) ? bk : bv;
    const f16* __restrict__ W      = WT + (size_t)z * D * D;
    const float scale = (z == 0) ? qscale : 1.0f;

    const int t = threadIdx.x;
    const int l = t & 63, w = t >> 6;
    const int i16 = l & 15, g = l >> 4;
    const int wm = w >> 1, wn = w & 1;
    const int m0 = blockIdx.x * 128, n0 = blockIdx.y * 128;

    f32x4 acc[4][4] = {};

    float4 ar[4];
    f16x8  br[2];

    auto load_stage = [&](int kt) {
        const int k0 = kt * 32;
#pragma unroll
        for (int r = 0; r < 4; ++r) {
            int ch = t + 256 * r, row = ch >> 3, c4 = ch & 7;
            ar[r] = *reinterpret_cast<const float4*>(A + (size_t)(m0 + row) * D + k0 + c4 * 4);
        }
#pragma unroll
        for (int r = 0; r < 2; ++r) {
            int ch = t + 256 * r, row = ch >> 2, c8 = ch & 3;
            br[r] = *reinterpret_cast<const f16x8*>(W + (size_t)(n0 + row) * D + k0 + c8 * 8);
        }
    };
    auto write_stage = [&](int buf) {
#pragma unroll
        for (int r = 0; r < 4; ++r) {
            int ch = t + 256 * r, row = ch >> 3, c4 = ch & 7;
            f16x4 hv;
            hv[0] = (f16)ar[r].x; hv[1] = (f16)ar[r].y; hv[2] = (f16)ar[r].z; hv[3] = (f16)ar[r].w;
            *reinterpret_cast<f16x4*>(&As[buf][row][c4 * 4]) = hv;
        }
#pragma unroll
        for (int r = 0; r < 2; ++r) {
            int ch = t + 256 * r, row = ch >> 2, c8 = ch & 3;
            *reinterpret_cast<f16x8*>(&Bs[buf][row][c8 * 8]) = br[r];
        }
    };

    load_stage(0);
    write_stage(0);
    __syncthreads();

    for (int kt = 0; kt < 16; ++kt) {
        const int cur = kt & 1;
        if (kt < 15) load_stage(kt + 1);

        f16x8 af[4], bf[4];
#pragma unroll
        for (int i = 0; i < 4; ++i)
            af[i] = *reinterpret_cast<const f16x8*>(&As[cur][wm * 64 + i * 16 + i16][g * 8]);
#pragma unroll
        for (int j = 0; j < 4; ++j)
            bf[j] = *reinterpret_cast<const f16x8*>(&Bs[cur][wn * 64 + j * 16 + i16][g * 8]);
#pragma unroll
        for (int i = 0; i < 4; ++i)
#pragma unroll
            for (int j = 0; j < 4; ++j)
                acc[i][j] = __builtin_amdgcn_mfma_f32_16x16x32_f16(af[i], bf[j], acc[i][j], 0, 0, 0);

        if (kt < 15) write_stage(cur ^ 1);
        __syncthreads();
    }

    float bvv[4];
#pragma unroll
    for (int j = 0; j < 4; ++j) bvv[j] = bias[n0 + wn * 64 + j * 16 + i16];

    if (z < 2) {
        f16* __restrict__ out = (z == 0) ? q16 : k16;
#pragma unroll
        for (int i = 0; i < 4; ++i) {
#pragma unroll
            for (int j = 0; j < 4; ++j) {
                const int nn = n0 + wn * 64 + j * 16 + i16;
#pragma unroll
                for (int e = 0; e < 4; ++e) {
                    const int mr = m0 + wm * 64 + i * 16 + g * 4 + e;
                    out[(size_t)mr * D + nn] = (f16)((acc[i][j][e] + bvv[j]) * scale);
                }
            }
        }
    } else {
        // transposed store: vT[(b*512 + n)*1024 + j_in_seq]
#pragma unroll
        for (int i = 0; i < 4; ++i) {
            const int mr = m0 + wm * 64 + i * 16 + g * 4;  // 4 consecutive rows via e
            const int bb = mr >> 10, jj = mr & 1023;
#pragma unroll
            for (int j = 0; j < 4; ++j) {
                const int nn = n0 + wn * 64 + j * 16 + i16;
                f16x4 hv;
#pragma unroll
                for (int e = 0; e < 4; ++e) hv[e] = (f16)(acc[i][j][e] + bvv[j]);
                *reinterpret_cast<f16x4*>(vT + ((size_t)(bb * D + nn)) * S + jj) = hv;
            }
        }
    }
}

// ---------------------------------------------------------------------------
// Kernel 4: fused flash attention with temporal bias.
// R2: Q-tile 32/block (16 rows/wave), 1024 blocks -> 4 blocks/CU = 8 waves/CU
// (was 2 blocks/CU = 4 waves: latency-bound at Occupancy 10.8%, MfmaUtil 3.7%).
// td float4 loads prefetched one KV-tile ahead into registers (T14): issued
// after the K/V stage loads so the stage_write's vmcnt wait leaves them in
// flight; consumed a full iteration later.  LDS Tab dropped (lin fast path
// covers bt1==0 inputs; non-lin falls back to global-table interp).
// ---------------------------------------------------------------------------
__global__ __launch_bounds__(128, 2) void attn_kernel(
    const f16* __restrict__ q16, const f16* __restrict__ k16, const f16* __restrict__ vT,
    const float* __restrict__ td, const float* __restrict__ tabg, const float* __restrict__ coef,
    f16* __restrict__ out16)
{
    __shared__ f16 Ks[2][32][72];
    __shared__ f16 Vs[2][64][40];
    __shared__ f16 Ps[2][16][40];

    // XCD-aware decode: blocks of same b land on same XCD pair (td/K/V L2 reuse)
    const int bid = blockIdx.x;
    const int xs = bid & 7, rest = bid >> 3;     // rest in [0,128)
    const int b = xs >> 1;
    const int h = rest & 7;
    const int it = ((rest >> 3) << 1) | (xs & 1);   // [0,32)

    const int t = threadIdx.x;
    const int w = t >> 6, l = t & 63;
    const int i16 = l & 15, g = l >> 4;

    const float cH = coef[h], dH = coef[8 + h];
    const int lin = ((const int*)coef)[16 + h];
    const float* __restrict__ th = tabg + h * 1032;

    const int qrow = it * 32 + w * 16 + i16;

    f16x8 qf[2];
#pragma unroll
    for (int kf = 0; kf < 2; ++kf)
        qf[kf] = *reinterpret_cast<const f16x8*>(
            q16 + (size_t)(b * S + qrow) * D + h * 64 + kf * 32 + g * 8);

    float mr = -1e30f, lr = 0.f;
    f32x4 o[4] = {};

    f16x8 sk[2], sv[2];
    int krow[2], kc8[2], vdv[2], vj8[2];
#pragma unroll
    for (int r = 0; r < 2; ++r) {
        int ch = t + 128 * r;
        krow[r] = ch >> 3; kc8[r] = ch & 7;
        vdv[r]  = ch >> 2; vj8[r] = ch & 3;
    }

    auto stage_load = [&](int jt) {
#pragma unroll
        for (int r = 0; r < 2; ++r)
            sk[r] = *reinterpret_cast<const f16x8*>(
                k16 + (size_t)(b * S + jt * 32 + krow[r]) * D + h * 64 + kc8[r] * 8);
#pragma unroll
        for (int r = 0; r < 2; ++r)
            sv[r] = *reinterpret_cast<const f16x8*>(
                vT + (size_t)(b * D + h * 64 + vdv[r]) * S + jt * 32 + vj8[r] * 8);
    };
    auto stage_write = [&](int buf) {
#pragma unroll
        for (int r = 0; r < 2; ++r)
            *reinterpret_cast<f16x8*>(&Ks[buf][krow[r]][kc8[r] * 8]) = sk[r];
#pragma unroll
        for (int r = 0; r < 2; ++r)
            *reinterpret_cast<f16x8*>(&Vs[buf][vdv[r]][vj8[r] * 8]) = sv[r];
    };

    // td row pointer for this lane: 8 values per KV-tile (2 x float4)
    const float* __restrict__ tdrow = td + (size_t)(b * S + qrow) * S + g * 4;

    float4 tr0, tr1, tn0, tn1;

    stage_load(0);
    tr0 = *reinterpret_cast<const float4*>(tdrow);
    tr1 = *reinterpret_cast<const float4*>(tdrow + 16);
    stage_write(0);
    __syncthreads();

    for (int jt = 0; jt < 32; ++jt) {
        const int cur = jt & 1;
        if (jt < 31) {
            stage_load(jt + 1);
            tn0 = *reinterpret_cast<const float4*>(tdrow + (jt + 1) * 32);
            tn1 = *reinterpret_cast<const float4*>(tdrow + (jt + 1) * 32 + 16);
        }

        // ---- S^T = K * Q^T  (rows = kv j, cols = q-row i) ----
        f32x4 s[2];
#pragma unroll
        for (int fj = 0; fj < 2; ++fj) {
            f16x8 ka0 = *reinterpret_cast<const f16x8*>(&Ks[cur][fj * 16 + i16][g * 8]);
            f16x8 ka1 = *reinterpret_cast<const f16x8*>(&Ks[cur][fj * 16 + i16][32 + g * 8]);
            f32x4 zz = {0.f, 0.f, 0.f, 0.f};
            zz = __builtin_amdgcn_mfma_f32_16x16x32_f16(ka0, qf[0], zz, 0, 0, 0);
            s[fj] = __builtin_amdgcn_mfma_f32_16x16x32_f16(ka1, qf[1], zz, 0, 0, 0);
        }

        // ---- bias + online softmax (per-lane q-row i = lane&15) ----
        float pvv[2][4];
        float tmax = -1e30f;
#pragma unroll
        for (int fj = 0; fj < 2; ++fj) {
            const float4 t4 = fj ? tr1 : tr0;
            float tarr[4] = {t4.x, t4.y, t4.z, t4.w};
#pragma unroll
            for (int e = 0; e < 4; ++e) {
                float u = fminf(fmaxf(tarr[e], 0.f), 1.f);
                float bias;
                if (lin) {
                    bias = fmaf(u, cH, dH);
                } else {
                    float x = u * 1024.f;
                    int ix = (int)x;
                    ix = (ix > 1023) ? 1023 : ix;
                    float fr = x - (float)ix;
                    float t0 = th[ix], t1 = th[ix + 1];
                    bias = fmaf(fr, t1 - t0, t0);
                }
                float vsc = s[fj][e] + bias;
                pvv[fj][e] = vsc;
                tmax = fmaxf(tmax, vsc);
            }
        }
        tmax = fmaxf(tmax, __shfl_xor(tmax, 16));
        tmax = fmaxf(tmax, __shfl_xor(tmax, 32));
        float mnew = fmaxf(mr, tmax);
        float alpha = exp2f(mr - mnew);
        mr = mnew;

        float rsum = 0.f;
        f16x4 pq[2];
#pragma unroll
        for (int fj = 0; fj < 2; ++fj)
#pragma unroll
            for (int e = 0; e < 4; ++e) {
                float p = exp2f(pvv[fj][e] - mnew);
                rsum += p;
                pq[fj][e] = (f16)p;
            }
        rsum += __shfl_xor(rsum, 16);
        rsum += __shfl_xor(rsum, 32);
        lr = lr * alpha + rsum;
#pragma unroll
        for (int fv = 0; fv < 4; ++fv) o[fv] *= alpha;

        // P^T relay through per-wave LDS (no barrier needed within wave)
#pragma unroll
        for (int fj = 0; fj < 2; ++fj)
            *reinterpret_cast<f16x4*>(&Ps[w][i16][fj * 16 + g * 4]) = pq[fj];

        f16x8 pb = *reinterpret_cast<const f16x8*>(&Ps[w][i16][g * 8]);

        // ---- out^T += V^T * P^T ----
#pragma unroll
        for (int fv = 0; fv < 4; ++fv) {
            f16x8 va = *reinterpret_cast<const f16x8*>(&Vs[cur][fv * 16 + i16][g * 8]);
            o[fv] = __builtin_amdgcn_mfma_f32_16x16x32_f16(va, pb, o[fv], 0, 0, 0);
        }

        if (jt < 31) stage_write(cur ^ 1);
        __syncthreads();
        tr0 = tn0; tr1 = tn1;
    }

    // epilogue: out[i][dv] = o^T / lsum
    const float rl = 1.f / lr;
#pragma unroll
    for (int fv = 0; fv < 4; ++fv) {
        f16x4 hv;
#pragma unroll
        for (int e = 0; e < 4; ++e) hv[e] = (f16)(o[fv][e] * rl);
        *reinterpret_cast<f16x4*>(
            out16 + (size_t)(b * S + qrow) * D + h * 64 + fv * 16 + g * 4) = hv;
    }
}

// ---------------------------------------------------------------------------
// Kernel 5: output projection.  out(f32) = attn16(f16) @ Wo + bo
// ---------------------------------------------------------------------------
__global__ __launch_bounds__(256) void final_gemm(const f16* __restrict__ A, const f16* __restrict__ WoT,
                                                  const float* __restrict__ bo, float* __restrict__ out)
{
    __shared__ f16 As[2][128][40];
    __shared__ f16 Bs[2][128][40];

    const int t = threadIdx.x;
    const int l = t & 63, w = t >> 6;
    const int i16 = l & 15, g = l >> 4;
    const int wm = w >> 1, wn = w & 1;
    const int m0 = blockIdx.x * 128, n0 = blockIdx.y * 128;

    f32x4 acc[4][4] = {};
    f16x8 ar[2], br[2];

    auto load_stage = [&](int kt) {
        const int k0 = kt * 32;
#pragma unroll
        for (int r = 0; r < 2; ++r) {
            int ch = t + 256 * r, row = ch >> 2, c8 = ch & 3;
            ar[r] = *reinterpret_cast<const f16x8*>(A + (size_t)(m0 + row) * D + k0 + c8 * 8);
            br[r] = *reinterpret_cast<const f16x8*>(WoT + (size_t)(n0 + row) * D + k0 + c8 * 8);
        }
    };
    auto write_stage = [&](int buf) {
#pragma unroll
        for (int r = 0; r < 2; ++r) {
            int ch = t + 256 * r, row = ch >> 2, c8 = ch & 3;
            *reinterpret_cast<f16x8*>(&As[buf][row][c8 * 8]) = ar[r];
            *reinterpret_cast<f16x8*>(&Bs[buf][row][c8 * 8]) = br[r];
        }
    };

    load_stage(0);
    write_stage(0);
    __syncthreads();

    for (int kt = 0; kt < 16; ++kt) {
        const int cur = kt & 1;
        if (kt < 15) load_stage(kt + 1);

        f16x8 af[4], bf[4];
#pragma unroll
        for (int i = 0; i < 4; ++i)
            af[i] = *reinterpret_cast<const f16x8*>(&As[cur][wm * 64 + i * 16 + i16][g * 8]);
#pragma unroll
        for (int j = 0; j < 4; ++j)
            bf[j] = *reinterpret_cast<const f16x8*>(&Bs[cur][wn * 64 + j * 16 + i16][g * 8]);
#pragma unroll
        for (int i = 0; i < 4; ++i)
#pragma unroll
            for (int j = 0; j < 4; ++j)
                acc[i][j] = __builtin_amdgcn_mfma_f32_16x16x32_f16(af[i], bf[j], acc[i][j], 0, 0, 0);

        if (kt < 15) write_stage(cur ^ 1);
        __syncthreads();
    }

    float bvv[4];
#pragma unroll
    for (int j = 0; j < 4; ++j) bvv[j] = bo[n0 + wn * 64 + j * 16 + i16];

#pragma unroll
    for (int i = 0; i < 4; ++i) {
#pragma unroll
        for (int j = 0; j < 4; ++j) {
            const int nn = n0 + wn * 64 + j * 16 + i16;
#pragma unroll
            for (int e = 0; e < 4; ++e) {
                const int mr = m0 + wm * 64 + i * 16 + g * 4 + e;
                out[(size_t)mr * D + nn] = acc[i][j][e] + bvv[j];
            }
        }
    }
}

// ---------------------------------------------------------------------------
extern "C" void kernel_launch(void* const* d_in, const int* in_sizes, int n_in,
                              void* d_out, int out_size, void* d_ws, size_t ws_size,
                              hipStream_t stream)
{
    (void)in_sizes; (void)n_in; (void)out_size; (void)ws_size; // needs ~19 MB of ws

    const float* query = (const float*)d_in[0];
    const float* key_  = (const float*)d_in[1];
    const float* value = (const float*)d_in[2];
    const float* td    = (const float*)d_in[3];
    const float* Wq  = (const float*)d_in[4];  const float* bq  = (const float*)d_in[5];
    const float* Wk  = (const float*)d_in[6];  const float* bk  = (const float*)d_in[7];
    const float* Wv  = (const float*)d_in[8];  const float* bv  = (const float*)d_in[9];
    const float* Wo  = (const float*)d_in[10]; const float* bo  = (const float*)d_in[11];
    const float* Wt1 = (const float*)d_in[12]; const float* bt1 = (const float*)d_in[13];
    const float* Wt2 = (const float*)d_in[14]; const float* bt2 = (const float*)d_in[15];
    float* out = (float*)d_out;

    char* ws = (char*)d_ws;
    f16*   WT   = (f16*)(ws + OFF_WT);
    f16*   q16  = (f16*)(ws + OFF_Q16);
    f16*   k16  = (f16*)(ws + OFF_K16);
    f16*   vT   = (f16*)(ws + OFF_VT);
    f16*   at16 = (f16*)(ws + OFF_AT);
    float* tab  = (float*)(ws + OFF_TAB);
    float* coef = (float*)(ws + OFF_COEF);

    wtrans<<<dim3(8, 8, 4), 256, 0, stream>>>(Wq, Wk, Wv, Wo, WT);
    build_table<<<1, 1024, 0, stream>>>(Wt1, bt1, Wt2, bt2, tab, coef);
    proj_gemm<<<dim3(32, 4, 3), 256, 0, stream>>>(query, key_, value, WT, bq, bk, bv,
                                                  q16, k16, vT, 0.125f * L2E);
    attn_kernel<<<1024, 128, 0, stream>>>(q16, k16, vT, td, tab, coef, at16);
    final_gemm<<<dim3(32, 4), 256, 0, stream>>>(at16, WT + 3ull * (size_t)D * D, bo, out);
}